// Round 6
// baseline (334.982 us; speedup 1.0000x reference)
//
#include <hip/hip_runtime.h>
#include <hip/hip_bf16.h>
#include <math.h>

#define N_NODES 50000
#define N_EDGES 1600000
#define IN_CH   128
#define OUT_CH  64
#define N_HEADS 4
#define CH      (N_HEADS * OUT_CH)   // 256

#define NPB   32                     // nodes per bin
#define BINS  1563                   // ceil(50000/32)
#define CAPB  1536                   // per-bin edge capacity (avg 1024, sigma~32 -> +16 sigma)
#define CHUNK 20000                  // edges per scatter block (80 * 20000 = 1.6M)
#define NSCAT 80                     // N_EDGES / CHUNK
#define GEMMB 782                    // (N_NODES + 63) / 64

typedef __attribute__((ext_vector_type(8))) short bf16x8;
typedef __attribute__((ext_vector_type(4))) float f32x4;

// ---------- helpers ----------
__device__ __forceinline__ float bf16_lo(unsigned u) { return __uint_as_float(u << 16); }
__device__ __forceinline__ float bf16_hi(unsigned u) { return __uint_as_float(u & 0xffff0000u); }
__device__ __forceinline__ unsigned short f_to_bf16(float f) {
  unsigned u = __float_as_uint(f);
  u += 0x7fffu + ((u >> 16) & 1u);   // RNE
  return (unsigned short)(u >> 16);
}

// ---------- kernel 1: W swizzle (fp32 [4][128][64] -> bf16 B-frag order) + cursor init ----------
__global__ __launch_bounds__(256) void convert_w_init(
    const float* __restrict__ w, unsigned short* __restrict__ wb, int* __restrict__ gcur)
{
  int i = blockIdx.x * 256 + threadIdx.x;          // 32768 total
  if (i < BINS) gcur[i] = i * CAPB;
  if (i >= N_HEADS * IN_CH * OUT_CH) return;
  int j = i & 7, lane = (i >> 3) & 63, ctg = (i >> 9) & 15, kc = i >> 13;
  int k = kc * 32 + (lane >> 4) * 8 + j;
  int n = ctg * 16 + (lane & 15);
  int h = n >> 6, o = n & 63;
  wb[i] = f_to_bf16(w[(h * IN_CH + k) * OUT_CH + o]);
}

// ---------- kernel 2: fused {binned ranked scatter | MFMA GEMM} ----------
// blocks [0, NSCAT)          : edge binning. CHUNK=20000 -> per-bin runs ~13 edges
//                              (~102B) so 64B lines of `binned` are fully written
//                              while L2-resident: full-line writeback, no RMW storm.
// blocks [NSCAT, NSCAT+GEMMB): MFMA GEMM + epilogue
// Shared-memory overlay: gemm needs 32 KB (tlds); scatter 12.5 KB (hist+base).
__global__ __launch_bounds__(256) void gemm_scatter(
    const float* __restrict__ x, const unsigned short* __restrict__ wb,
    const float* __restrict__ aw,
    unsigned short* __restrict__ xmsg, float* __restrict__ sbuf, float* __restrict__ tbuf,
    const int* __restrict__ etgt, const int* __restrict__ esrc,
    const float* __restrict__ eval, int* __restrict__ gcur, int2* __restrict__ binned)
{
  __shared__ __align__(16) char smem[32768];

  if (blockIdx.x < NSCAT) {
    // ---- edge binning ----
    int* lhist = (int*)smem;                               // BINS ints (6252 B)
    int* lbase = lhist + BINS;                             // BINS ints (6252 B)

    const int tid = threadIdx.x;
    const int e0 = blockIdx.x * CHUNK;
    const int n = min(CHUNK, N_EDGES - e0);

    for (int b = tid; b < BINS; b += 256) lhist[b] = 0;
    __syncthreads();

    // pass 1: histogram (coalesced etgt read; slice is L2-resident for pass 2)
    for (int i = tid; i < n; i += 256)
      atomicAdd(&lhist[etgt[e0 + i] >> 5], 1);
    __syncthreads();

    for (int b = tid; b < BINS; b += 256) {
      int c = lhist[b];
      lbase[b] = c ? atomicAdd(&gcur[b], c) : 0;
      lhist[b] = 0;                        // reuse as rank counter
    }
    __syncthreads();

    // pass 2: ranked scatter (etgt re-read hits L2)
    for (int i = tid; i < n; i += 256) {
      int t = etgt[e0 + i];
      int b = t >> 5;
      int r = atomicAdd(&lhist[b], 1);
      int pos = lbase[b] + r;
      if (pos < (b + 1) * CAPB) {          // overflow guard
        int pack = esrc[e0 + i] | ((t & 31) << 16);
        binned[pos] = make_int2(pack, __float_as_int(eval[e0 + i]));
      }
    }
    return;
  }

  // ---- MFMA GEMM ----
  unsigned short (*tlds)[32][128] = (unsigned short (*)[32][128])smem;  // [4][32][128]

  const int gbid = blockIdx.x - NSCAT;
  const int lane = threadIdx.x & 63;
  const int wv   = threadIdx.x >> 6;
  const int q    = lane >> 4;
  const int l16  = lane & 15;
  const int rowbase = gbid * 64 + (wv >> 1) * 32;
  const int chalf   = wv & 1;

  // A-frags: A[m=lane&15][k=q*8+j], fp32 loads -> bf16
  bf16x8 afrag[2][4];
  #pragma unroll
  for (int s = 0; s < 2; ++s) {
    int r = rowbase + s * 16 + l16;
    r = min(r, N_NODES - 1);
    const float* xp = x + (size_t)r * IN_CH + q * 8;
    #pragma unroll
    for (int kc = 0; kc < 4; ++kc) {
      f32x4 lo = *(const f32x4*)(xp + kc * 32);
      f32x4 hi = *(const f32x4*)(xp + kc * 32 + 4);
      bf16x8 a;
      a[0] = (short)f_to_bf16(lo[0]); a[1] = (short)f_to_bf16(lo[1]);
      a[2] = (short)f_to_bf16(lo[2]); a[3] = (short)f_to_bf16(lo[3]);
      a[4] = (short)f_to_bf16(hi[0]); a[5] = (short)f_to_bf16(hi[1]);
      a[6] = (short)f_to_bf16(hi[2]); a[7] = (short)f_to_bf16(hi[3]);
      afrag[s][kc] = a;
    }
  }

  f32x4 acc[2][8];
  #pragma unroll
  for (int s = 0; s < 2; ++s)
    #pragma unroll
    for (int ct = 0; ct < 8; ++ct)
      acc[s][ct] = (f32x4){0.f, 0.f, 0.f, 0.f};

  #pragma unroll
  for (int kc = 0; kc < 4; ++kc) {
    #pragma unroll
    for (int ct = 0; ct < 8; ++ct) {
      const int ctg = chalf * 8 + ct;
      bf16x8 b = *(const bf16x8*)(wb + ((size_t)(kc * 16 + ctg) * 64 + lane) * 8);
      acc[0][ct] = __builtin_amdgcn_mfma_f32_16x16x32_bf16(afrag[0][kc], b, acc[0][ct], 0, 0, 0);
      acc[1][ct] = __builtin_amdgcn_mfma_f32_16x16x32_bf16(afrag[1][kc], b, acc[1][ct], 0, 0, 0);
    }
  }

  // stage C-tile (bf16) into LDS; C/D layout: col=l16, row=q*4+reg
  #pragma unroll
  for (int s = 0; s < 2; ++s)
    #pragma unroll
    for (int ct = 0; ct < 8; ++ct)
      #pragma unroll
      for (int reg = 0; reg < 4; ++reg)
        tlds[wv][s * 16 + q * 4 + reg][ct * 16 + l16] = f_to_bf16(acc[s][ct][reg]);

  // fused s,t attention terms (register path)
  #pragma unroll
  for (int s = 0; s < 2; ++s) {
    float ps[2][4] = {{0,0,0,0},{0,0,0,0}};
    float pt[2][4] = {{0,0,0,0},{0,0,0,0}};
    #pragma unroll
    for (int ct = 0; ct < 8; ++ct) {
      int col = chalf * 128 + ct * 16 + l16;
      int h = col >> 6;
      float as_ = aw[h * 128 + (col & 63)];
      float at_ = aw[h * 128 + 64 + (col & 63)];
      int hp = ct >> 2;
      #pragma unroll
      for (int reg = 0; reg < 4; ++reg) {
        float v = acc[s][ct][reg];
        ps[hp][reg] += v * as_;
        pt[hp][reg] += v * at_;
      }
    }
    #pragma unroll
    for (int hp = 0; hp < 2; ++hp)
      #pragma unroll
      for (int reg = 0; reg < 4; ++reg)
        #pragma unroll
        for (int off = 1; off < 16; off <<= 1) {
          ps[hp][reg] += __shfl_xor(ps[hp][reg], off);
          pt[hp][reg] += __shfl_xor(pt[hp][reg], off);
        }
    const int rowq = rowbase + s * 16 + q * 4;
    if (l16 == 0) {
      #pragma unroll
      for (int reg = 0; reg < 4; ++reg) {
        int r = rowq + reg;
        if (r < N_NODES) {
          #pragma unroll
          for (int hp = 0; hp < 2; ++hp) {
            sbuf[r * 4 + chalf * 2 + hp] = ps[hp][reg];
            tbuf[r * 4 + chalf * 2 + hp] = pt[hp][reg];
          }
        }
      }
    }
  }

  __syncthreads();

  // coalesced xmsg store: 2 rows / instruction, 256B contiguous per half-wave
  const int seg  = lane & 31;
  const int half = lane >> 5;
  #pragma unroll
  for (int r2 = 0; r2 < 16; ++r2) {
    int row = r2 * 2 + half;
    int gr = rowbase + row;
    if (gr < N_NODES) {
      ushort4 vv = *(const ushort4*)&tlds[wv][row][seg * 4];
      *(ushort4*)(xmsg + (size_t)gr * CH + chalf * 128 + seg * 4) = vv;
    }
  }
}

// ---------- kernel 3: fused per-bin LDS counting sort + online-softmax aggregation ----------
// One 256-thread block per 32-node bin. 4 waves x 8 nodes each; 16-edge inner stage
// keeps 8 uint4 gathers in flight per lane (latency-bound per R5 counters).
__global__ __launch_bounds__(256) void bin_aggregate(
    const int* __restrict__ gcur, const int2* __restrict__ binned,
    const float* __restrict__ sbuf, const float* __restrict__ tbuf,
    const unsigned short* __restrict__ xmsg, float* __restrict__ out)
{
  __shared__ int nh[NPB];
  __shared__ int start_l[NPB];
  __shared__ int deg_l[NPB];
  __shared__ __align__(16) int2 sorted[CAPB];          // 12 KB
  __shared__ int s_lds[4][64];
  __shared__ __align__(16) float p_lds[4][64][4];

  const int tid = threadIdx.x;
  const int b = blockIdx.x;
  const int bbase = b * CAPB;
  const int cnt = min(gcur[b] - bbase, CAPB);

  if (tid < NPB) nh[tid] = 0;
  __syncthreads();

  // pass 1: per-node histogram (coalesced 8B reads; second pass hits L2)
  for (int i = tid; i < cnt; i += 256) {
    int2 e = binned[bbase + i];
    atomicAdd(&nh[(e.x >> 16) & 31], 1);
  }
  __syncthreads();

  if (tid < NPB) {                      // lanes 0..31 of wave 0: exclusive prefix
    int v = nh[tid];
    int sc = v;
    #pragma unroll
    for (int off = 1; off < NPB; off <<= 1) {
      int u = __shfl_up(sc, off);
      if (tid >= off) sc += u;
    }
    start_l[tid] = sc - v;
    deg_l[tid] = v;
    nh[tid] = 0;                        // reuse as rank counter
  }
  __syncthreads();

  // pass 2: counting sort into LDS (second global read hits L2)
  for (int i = tid; i < cnt; i += 256) {
    int2 e = binned[bbase + i];
    int tl = (e.x >> 16) & 31;
    int r = atomicAdd(&nh[tl], 1);
    sorted[start_l[tl] + r] = e;
  }
  __syncthreads();

  // ---- aggregation: 4 waves x 8 nodes each, edges from LDS ----
  const int lane = tid & 63;
  const int wave = tid >> 6;
  const int seg  = lane & 31;
  const int half = lane >> 5;
  const int hh4  = seg >> 3;            // head of this lane's 8 channels

#define GATHER2(sa, sb, idxa, idxb)                                                   \
  {                                                                                   \
    uint4 rA = *(const uint4*)(xmsg + (size_t)(sa) * CH + seg * 8);                   \
    uint4 rB = *(const uint4*)(xmsg + (size_t)(sb) * CH + seg * 8);                   \
    float qA = p_lds[wave][idxa][hh4];                                                \
    float qB = p_lds[wave][idxb][hh4];                                                \
    acc[0] = fmaf(qA, bf16_lo(rA.x), acc[0]); acc[1] = fmaf(qA, bf16_hi(rA.x), acc[1]); \
    acc[2] = fmaf(qA, bf16_lo(rA.y), acc[2]); acc[3] = fmaf(qA, bf16_hi(rA.y), acc[3]); \
    acc[4] = fmaf(qA, bf16_lo(rA.z), acc[4]); acc[5] = fmaf(qA, bf16_hi(rA.z), acc[5]); \
    acc[6] = fmaf(qA, bf16_lo(rA.w), acc[6]); acc[7] = fmaf(qA, bf16_hi(rA.w), acc[7]); \
    acc[0] = fmaf(qB, bf16_lo(rB.x), acc[0]); acc[1] = fmaf(qB, bf16_hi(rB.x), acc[1]); \
    acc[2] = fmaf(qB, bf16_lo(rB.y), acc[2]); acc[3] = fmaf(qB, bf16_hi(rB.y), acc[3]); \
    acc[4] = fmaf(qB, bf16_lo(rB.z), acc[4]); acc[5] = fmaf(qB, bf16_hi(rB.z), acc[5]); \
    acc[6] = fmaf(qB, bf16_lo(rB.w), acc[6]); acc[7] = fmaf(qB, bf16_hi(rB.w), acc[7]); \
  }

  for (int ni = wave * 8; ni < wave * 8 + 8; ++ni) {
    const int n = b * NPB + ni;
    if (n >= N_NODES) break;            // wave-uniform; only last bin is short

    const int d   = deg_l[ni];
    const int rs0 = start_l[ni];

    float4 tn4 = *(const float4*)(tbuf + (size_t)n * 4);
    float tn[4] = {tn4.x, tn4.y, tn4.z, tn4.w};

    float m[4]    = {-INFINITY, -INFINITY, -INFINITY, -INFINITY};
    float psum[4] = {0.f, 0.f, 0.f, 0.f};
    float acc[8]  = {0.f, 0.f, 0.f, 0.f, 0.f, 0.f, 0.f, 0.f};

    for (int base2 = 0; base2 < d; base2 += 64) {
      const int cnt2 = min(64, d - base2);
      const bool act = lane < cnt2;

      float sc4[4] = {-INFINITY, -INFINITY, -INFINITY, -INFINITY};
      int s = 0;
      if (act) {
        int2 ev = sorted[rs0 + base2 + lane];
        s = ev.x & 0xffff;
        float v = __int_as_float(ev.y);
        float4 sv4 = *(const float4*)(sbuf + (size_t)s * 4);
        float svv[4] = {sv4.x, sv4.y, sv4.z, sv4.w};
        #pragma unroll
        for (int hh = 0; hh < 4; ++hh) {
          float t = svv[hh] + tn[hh];
          t = (t > 0.f) ? t : 0.01f * t;           // leaky_relu
          sc4[hh] = t * v;
        }
      }

      float bm[4] = {sc4[0], sc4[1], sc4[2], sc4[3]};
      #pragma unroll
      for (int hh = 0; hh < 4; ++hh)
        #pragma unroll
        for (int off = 32; off; off >>= 1)
          bm[hh] = fmaxf(bm[hh], __shfl_xor(bm[hh], off));

      float p[4];
      #pragma unroll
      for (int hh = 0; hh < 4; ++hh) {
        float nm = fmaxf(m[hh], bm[hh]);
        float r = (m[hh] == -INFINITY) ? 0.f : __expf(m[hh] - nm);
        psum[hh] *= r;
        if (hh == hh4) {
          #pragma unroll
          for (int j = 0; j < 8; ++j) acc[j] *= r;
        }
        m[hh] = nm;
        p[hh] = act ? __expf(sc4[hh] - nm) : 0.f;
        psum[hh] += p[hh];
      }

      if (act) {
        s_lds[wave][lane] = s;
        *(float4*)(&p_lds[wave][lane][0]) = make_float4(p[0], p[1], p[2], p[3]);
      }
      __builtin_amdgcn_wave_barrier();

      int k = 0;
      // 16-edge stage: 8 independent uint4 gathers in flight per lane
      for (; k + 16 <= cnt2; k += 16) {
        int s0 = s_lds[wave][k + 0 + half];
        int s1 = s_lds[wave][k + 2 + half];
        int s2 = s_lds[wave][k + 4 + half];
        int s3 = s_lds[wave][k + 6 + half];
        int s4 = s_lds[wave][k + 8 + half];
        int s5 = s_lds[wave][k + 10 + half];
        int s6 = s_lds[wave][k + 12 + half];
        int s7 = s_lds[wave][k + 14 + half];
        uint4 r0 = *(const uint4*)(xmsg + (size_t)s0 * CH + seg * 8);
        uint4 r1 = *(const uint4*)(xmsg + (size_t)s1 * CH + seg * 8);
        uint4 r2 = *(const uint4*)(xmsg + (size_t)s2 * CH + seg * 8);
        uint4 r3 = *(const uint4*)(xmsg + (size_t)s3 * CH + seg * 8);
        uint4 r4 = *(const uint4*)(xmsg + (size_t)s4 * CH + seg * 8);
        uint4 r5 = *(const uint4*)(xmsg + (size_t)s5 * CH + seg * 8);
        uint4 r6 = *(const uint4*)(xmsg + (size_t)s6 * CH + seg * 8);
        uint4 r7 = *(const uint4*)(xmsg + (size_t)s7 * CH + seg * 8);
        float q0 = p_lds[wave][k + 0 + half][hh4];
        float q1 = p_lds[wave][k + 2 + half][hh4];
        float q2 = p_lds[wave][k + 4 + half][hh4];
        float q3 = p_lds[wave][k + 6 + half][hh4];
        float q4 = p_lds[wave][k + 8 + half][hh4];
        float q5 = p_lds[wave][k + 10 + half][hh4];
        float q6 = p_lds[wave][k + 12 + half][hh4];
        float q7 = p_lds[wave][k + 14 + half][hh4];
        acc[0] = fmaf(q0, bf16_lo(r0.x), acc[0]); acc[1] = fmaf(q0, bf16_hi(r0.x), acc[1]);
        acc[2] = fmaf(q0, bf16_lo(r0.y), acc[2]); acc[3] = fmaf(q0, bf16_hi(r0.y), acc[3]);
        acc[4] = fmaf(q0, bf16_lo(r0.z), acc[4]); acc[5] = fmaf(q0, bf16_hi(r0.z), acc[5]);
        acc[6] = fmaf(q0, bf16_lo(r0.w), acc[6]); acc[7] = fmaf(q0, bf16_hi(r0.w), acc[7]);
        acc[0] = fmaf(q1, bf16_lo(r1.x), acc[0]); acc[1] = fmaf(q1, bf16_hi(r1.x), acc[1]);
        acc[2] = fmaf(q1, bf16_lo(r1.y), acc[2]); acc[3] = fmaf(q1, bf16_hi(r1.y), acc[3]);
        acc[4] = fmaf(q1, bf16_lo(r1.z), acc[4]); acc[5] = fmaf(q1, bf16_hi(r1.z), acc[5]);
        acc[6] = fmaf(q1, bf16_lo(r1.w), acc[6]); acc[7] = fmaf(q1, bf16_hi(r1.w), acc[7]);
        acc[0] = fmaf(q2, bf16_lo(r2.x), acc[0]); acc[1] = fmaf(q2, bf16_hi(r2.x), acc[1]);
        acc[2] = fmaf(q2, bf16_lo(r2.y), acc[2]); acc[3] = fmaf(q2, bf16_hi(r2.y), acc[3]);
        acc[4] = fmaf(q2, bf16_lo(r2.z), acc[4]); acc[5] = fmaf(q2, bf16_hi(r2.z), acc[5]);
        acc[6] = fmaf(q2, bf16_lo(r2.w), acc[6]); acc[7] = fmaf(q2, bf16_hi(r2.w), acc[7]);
        acc[0] = fmaf(q3, bf16_lo(r3.x), acc[0]); acc[1] = fmaf(q3, bf16_hi(r3.x), acc[1]);
        acc[2] = fmaf(q3, bf16_lo(r3.y), acc[2]); acc[3] = fmaf(q3, bf16_hi(r3.y), acc[3]);
        acc[4] = fmaf(q3, bf16_lo(r3.z), acc[4]); acc[5] = fmaf(q3, bf16_hi(r3.z), acc[5]);
        acc[6] = fmaf(q3, bf16_lo(r3.w), acc[6]); acc[7] = fmaf(q3, bf16_hi(r3.w), acc[7]);
        acc[0] = fmaf(q4, bf16_lo(r4.x), acc[0]); acc[1] = fmaf(q4, bf16_hi(r4.x), acc[1]);
        acc[2] = fmaf(q4, bf16_lo(r4.y), acc[2]); acc[3] = fmaf(q4, bf16_hi(r4.y), acc[3]);
        acc[4] = fmaf(q4, bf16_lo(r4.z), acc[4]); acc[5] = fmaf(q4, bf16_hi(r4.z), acc[5]);
        acc[6] = fmaf(q4, bf16_lo(r4.w), acc[6]); acc[7] = fmaf(q4, bf16_hi(r4.w), acc[7]);
        acc[0] = fmaf(q5, bf16_lo(r5.x), acc[0]); acc[1] = fmaf(q5, bf16_hi(r5.x), acc[1]);
        acc[2] = fmaf(q5, bf16_lo(r5.y), acc[2]); acc[3] = fmaf(q5, bf16_hi(r5.y), acc[3]);
        acc[4] = fmaf(q5, bf16_lo(r5.z), acc[4]); acc[5] = fmaf(q5, bf16_hi(r5.z), acc[5]);
        acc[6] = fmaf(q5, bf16_lo(r5.w), acc[6]); acc[7] = fmaf(q5, bf16_hi(r5.w), acc[7]);
        acc[0] = fmaf(q6, bf16_lo(r6.x), acc[0]); acc[1] = fmaf(q6, bf16_hi(r6.x), acc[1]);
        acc[2] = fmaf(q6, bf16_lo(r6.y), acc[2]); acc[3] = fmaf(q6, bf16_hi(r6.y), acc[3]);
        acc[4] = fmaf(q6, bf16_lo(r6.z), acc[4]); acc[5] = fmaf(q6, bf16_hi(r6.z), acc[5]);
        acc[6] = fmaf(q6, bf16_lo(r6.w), acc[6]); acc[7] = fmaf(q6, bf16_hi(r6.w), acc[7]);
        acc[0] = fmaf(q7, bf16_lo(r7.x), acc[0]); acc[1] = fmaf(q7, bf16_hi(r7.x), acc[1]);
        acc[2] = fmaf(q7, bf16_lo(r7.y), acc[2]); acc[3] = fmaf(q7, bf16_hi(r7.y), acc[3]);
        acc[4] = fmaf(q7, bf16_lo(r7.z), acc[4]); acc[5] = fmaf(q7, bf16_hi(r7.z), acc[5]);
        acc[6] = fmaf(q7, bf16_lo(r7.w), acc[6]); acc[7] = fmaf(q7, bf16_hi(r7.w), acc[7]);
      }
      for (; k + 8 <= cnt2; k += 8) {
        int sA = s_lds[wave][k + 0 + half];
        int sB = s_lds[wave][k + 2 + half];
        int sC = s_lds[wave][k + 4 + half];
        int sD = s_lds[wave][k + 6 + half];
        GATHER2(sA, sB, k + 0 + half, k + 2 + half);
        GATHER2(sC, sD, k + 4 + half, k + 6 + half);
      }
      for (; k < cnt2; k += 2) {
        int e = k + half;
        if (e < cnt2) {
          int sA = s_lds[wave][e];
          uint4 rA = *(const uint4*)(xmsg + (size_t)sA * CH + seg * 8);
          float qA = p_lds[wave][e][hh4];
          acc[0] = fmaf(qA, bf16_lo(rA.x), acc[0]); acc[1] = fmaf(qA, bf16_hi(rA.x), acc[1]);
          acc[2] = fmaf(qA, bf16_lo(rA.y), acc[2]); acc[3] = fmaf(qA, bf16_hi(rA.y), acc[3]);
          acc[4] = fmaf(qA, bf16_lo(rA.z), acc[4]); acc[5] = fmaf(qA, bf16_hi(rA.z), acc[5]);
          acc[6] = fmaf(qA, bf16_lo(rA.w), acc[6]); acc[7] = fmaf(qA, bf16_hi(rA.w), acc[7]);
        }
      }
      __builtin_amdgcn_wave_barrier();
    }

    #pragma unroll
    for (int j = 0; j < 8; ++j) acc[j] += __shfl_xor(acc[j], 32);
    #pragma unroll
    for (int hh = 0; hh < 4; ++hh)
      #pragma unroll
      for (int off = 32; off; off >>= 1)
        psum[hh] += __shfl_xor(psum[hh], off);

    float rsum = psum[hh4];
    float inv = (rsum > 0.f) ? 1.0f / rsum : 0.f;
    const int o = half * 4;
    float4 o4 = make_float4(acc[o+0]*inv, acc[o+1]*inv, acc[o+2]*inv, acc[o+3]*inv);
    *(float4*)(out + (size_t)n * CH + seg * 8 + half * 4) = o4;
  }
#undef GATHER2
}

// ---------- launch ----------
extern "C" void kernel_launch(void* const* d_in, const int* in_sizes, int n_in,
                              void* d_out, int out_size, void* d_ws, size_t ws_size,
                              hipStream_t stream) {
  const float* x    = (const float*)d_in[0];
  const int*   etgt = (const int*)  d_in[1];
  const int*   esrc = (const int*)  d_in[2];
  const float* evl  = (const float*)d_in[3];
  const float* w    = (const float*)d_in[4];
  const float* aw   = (const float*)d_in[5];
  float* out = (float*)d_out;

  char* ws = (char*)d_ws;
  unsigned short* wb   = (unsigned short*)(ws);              //      65,536 B
  unsigned short* xmsg = (unsigned short*)(ws + 65536);      //  25,600,000 B
  float* sbuf     = (float*)(ws + 25665536);                 //     800,000 B
  float* tbuf     = (float*)(ws + 26465536);                 //     800,000 B
  int*   gcur     = (int*)  (ws + 27265536);                 //       8,192 B
  int2*  binned   = (int2*) (ws + 27273728);                 //  19,206,144 B
  // total used: 46,479,872 B

  convert_w_init<<<128, 256, 0, stream>>>(w, wb, gcur);
  gemm_scatter<<<NSCAT + GEMMB, 256, 0, stream>>>(x, wb, aw, xmsg, sbuf, tbuf,
                                                  etgt, esrc, evl, gcur, binned);
  bin_aggregate<<<BINS, 256, 0, stream>>>(gcur, binned, sbuf, tbuf, xmsg, out);
}

// Round 7
// 274.977 us; speedup vs baseline: 1.2182x; 1.2182x over previous
//
#include <hip/hip_runtime.h>
#include <hip/hip_bf16.h>
#include <math.h>

#define N_NODES 50000
#define N_EDGES 1600000
#define IN_CH   128
#define OUT_CH  64
#define N_HEADS 4
#define CH      (N_HEADS * OUT_CH)   // 256

#define NPB   64                     // nodes per bin
#define BINS  782                    // ceil(50000/64)
#define CAPB  3072                   // per-bin edge capacity (avg 2048, sigma~45)
#define CHUNK 8000                   // edges per scatter block (200 * 8000 = 1.6M)
#define NSCAT 200                    // N_EDGES / CHUNK
#define GEMMB 782                    // (N_NODES + 63) / 64

typedef __attribute__((ext_vector_type(8))) short bf16x8;
typedef __attribute__((ext_vector_type(4))) float f32x4;

// ---------- helpers ----------
__device__ __forceinline__ float bf16_lo(unsigned u) { return __uint_as_float(u << 16); }
__device__ __forceinline__ float bf16_hi(unsigned u) { return __uint_as_float(u & 0xffff0000u); }
__device__ __forceinline__ unsigned short f_to_bf16(float f) {
  unsigned u = __float_as_uint(f);
  u += 0x7fffu + ((u >> 16) & 1u);   // RNE
  return (unsigned short)(u >> 16);
}

// ---------- kernel 1: W swizzle (fp32 [4][128][64] -> bf16 B-frag order) + cursor init ----------
__global__ __launch_bounds__(256) void convert_w_init(
    const float* __restrict__ w, unsigned short* __restrict__ wb, int* __restrict__ gcur)
{
  int i = blockIdx.x * 256 + threadIdx.x;          // 32768 total
  if (i < BINS) gcur[i] = i * CAPB;
  if (i >= N_HEADS * IN_CH * OUT_CH) return;
  int j = i & 7, lane = (i >> 3) & 63, ctg = (i >> 9) & 15, kc = i >> 13;
  int k = kc * 32 + (lane >> 4) * 8 + j;
  int n = ctg * 16 + (lane & 15);
  int h = n >> 6, o = n & 63;
  wb[i] = f_to_bf16(w[(h * IN_CH + k) * OUT_CH + o]);
}

// ---------- kernel 2: fused {binned ranked scatter | MFMA GEMM} ----------
// blocks [0, NSCAT)          : edge binning. CHUNK=8000 -> per-bin runs ~10 edges
//                              (~80B) so binned 64B lines are mostly covered by one
//                              block's burst (less partial-line RMW / XCD ping-pong).
// blocks [NSCAT, NSCAT+GEMMB): MFMA GEMM + epilogue
// Shared-memory overlay: gemm needs 32 KB (tlds); scatter ~22.3 KB.
__global__ __launch_bounds__(256) void gemm_scatter(
    const float* __restrict__ x, const unsigned short* __restrict__ wb,
    const float* __restrict__ aw,
    unsigned short* __restrict__ xmsg, float* __restrict__ sbuf, float* __restrict__ tbuf,
    const int* __restrict__ etgt, const int* __restrict__ esrc,
    const float* __restrict__ eval, int* __restrict__ gcur, int2* __restrict__ binned)
{
  __shared__ __align__(16) char smem[32768];

  if (blockIdx.x < NSCAT) {
    // ---- edge binning ----
    int* lhist = (int*)smem;                               // BINS ints (3128 B)
    int* lbase = lhist + BINS;                             // BINS ints (3128 B)
    unsigned short* stg = (unsigned short*)(lbase + BINS); // CHUNK ushorts (16000 B)

    const int tid = threadIdx.x;
    const int e0 = blockIdx.x * CHUNK;
    const int n = min(CHUNK, N_EDGES - e0);

    for (int b = tid; b < BINS; b += 256) lhist[b] = 0;
    __syncthreads();

    for (int i = tid; i < n; i += 256) {
      int t = etgt[e0 + i];
      stg[i] = (unsigned short)t;
      atomicAdd(&lhist[t >> 6], 1);
    }
    __syncthreads();

    for (int b = tid; b < BINS; b += 256) {
      int c = lhist[b];
      lbase[b] = c ? atomicAdd(&gcur[b], c) : 0;
      lhist[b] = 0;                        // reuse as rank counter
    }
    __syncthreads();

    for (int i = tid; i < n; i += 256) {
      int t = (int)stg[i];
      int b = t >> 6;
      int r = atomicAdd(&lhist[b], 1);
      int pos = lbase[b] + r;
      if (pos < (b + 1) * CAPB) {          // overflow guard
        int pack = esrc[e0 + i] | ((t & 63) << 16);
        binned[pos] = make_int2(pack, __float_as_int(eval[e0 + i]));
      }
    }
    return;
  }

  // ---- MFMA GEMM ----
  unsigned short (*tlds)[32][128] = (unsigned short (*)[32][128])smem;  // [4][32][128]

  const int gbid = blockIdx.x - NSCAT;
  const int lane = threadIdx.x & 63;
  const int wv   = threadIdx.x >> 6;
  const int q    = lane >> 4;
  const int l16  = lane & 15;
  const int rowbase = gbid * 64 + (wv >> 1) * 32;
  const int chalf   = wv & 1;

  // A-frags: A[m=lane&15][k=q*8+j], fp32 loads -> bf16
  bf16x8 afrag[2][4];
  #pragma unroll
  for (int s = 0; s < 2; ++s) {
    int r = rowbase + s * 16 + l16;
    r = min(r, N_NODES - 1);
    const float* xp = x + (size_t)r * IN_CH + q * 8;
    #pragma unroll
    for (int kc = 0; kc < 4; ++kc) {
      f32x4 lo = *(const f32x4*)(xp + kc * 32);
      f32x4 hi = *(const f32x4*)(xp + kc * 32 + 4);
      bf16x8 a;
      a[0] = (short)f_to_bf16(lo[0]); a[1] = (short)f_to_bf16(lo[1]);
      a[2] = (short)f_to_bf16(lo[2]); a[3] = (short)f_to_bf16(lo[3]);
      a[4] = (short)f_to_bf16(hi[0]); a[5] = (short)f_to_bf16(hi[1]);
      a[6] = (short)f_to_bf16(hi[2]); a[7] = (short)f_to_bf16(hi[3]);
      afrag[s][kc] = a;
    }
  }

  f32x4 acc[2][8];
  #pragma unroll
  for (int s = 0; s < 2; ++s)
    #pragma unroll
    for (int ct = 0; ct < 8; ++ct)
      acc[s][ct] = (f32x4){0.f, 0.f, 0.f, 0.f};

  #pragma unroll
  for (int kc = 0; kc < 4; ++kc) {
    #pragma unroll
    for (int ct = 0; ct < 8; ++ct) {
      const int ctg = chalf * 8 + ct;
      bf16x8 b = *(const bf16x8*)(wb + ((size_t)(kc * 16 + ctg) * 64 + lane) * 8);
      acc[0][ct] = __builtin_amdgcn_mfma_f32_16x16x32_bf16(afrag[0][kc], b, acc[0][ct], 0, 0, 0);
      acc[1][ct] = __builtin_amdgcn_mfma_f32_16x16x32_bf16(afrag[1][kc], b, acc[1][ct], 0, 0, 0);
    }
  }

  // stage C-tile (bf16) into LDS; C/D layout: col=l16, row=q*4+reg
  #pragma unroll
  for (int s = 0; s < 2; ++s)
    #pragma unroll
    for (int ct = 0; ct < 8; ++ct)
      #pragma unroll
      for (int reg = 0; reg < 4; ++reg)
        tlds[wv][s * 16 + q * 4 + reg][ct * 16 + l16] = f_to_bf16(acc[s][ct][reg]);

  // fused s,t attention terms (register path)
  #pragma unroll
  for (int s = 0; s < 2; ++s) {
    float ps[2][4] = {{0,0,0,0},{0,0,0,0}};
    float pt[2][4] = {{0,0,0,0},{0,0,0,0}};
    #pragma unroll
    for (int ct = 0; ct < 8; ++ct) {
      int col = chalf * 128 + ct * 16 + l16;
      int h = col >> 6;
      float as_ = aw[h * 128 + (col & 63)];
      float at_ = aw[h * 128 + 64 + (col & 63)];
      int hp = ct >> 2;
      #pragma unroll
      for (int reg = 0; reg < 4; ++reg) {
        float v = acc[s][ct][reg];
        ps[hp][reg] += v * as_;
        pt[hp][reg] += v * at_;
      }
    }
    #pragma unroll
    for (int hp = 0; hp < 2; ++hp)
      #pragma unroll
      for (int reg = 0; reg < 4; ++reg)
        #pragma unroll
        for (int off = 1; off < 16; off <<= 1) {
          ps[hp][reg] += __shfl_xor(ps[hp][reg], off);
          pt[hp][reg] += __shfl_xor(pt[hp][reg], off);
        }
    const int rowq = rowbase + s * 16 + q * 4;
    if (l16 == 0) {
      #pragma unroll
      for (int reg = 0; reg < 4; ++reg) {
        int r = rowq + reg;
        if (r < N_NODES) {
          #pragma unroll
          for (int hp = 0; hp < 2; ++hp) {
            sbuf[r * 4 + chalf * 2 + hp] = ps[hp][reg];
            tbuf[r * 4 + chalf * 2 + hp] = pt[hp][reg];
          }
        }
      }
    }
  }

  __syncthreads();

  // coalesced xmsg store: 2 rows / instruction, 256B contiguous per half-wave
  const int seg  = lane & 31;
  const int half = lane >> 5;
  #pragma unroll
  for (int r2 = 0; r2 < 16; ++r2) {
    int row = r2 * 2 + half;
    int gr = rowbase + row;
    if (gr < N_NODES) {
      ushort4 vv = *(const ushort4*)&tlds[wv][row][seg * 4];
      *(ushort4*)(xmsg + (size_t)gr * CH + chalf * 128 + seg * 4) = vv;
    }
  }
}

// ---------- kernel 3: fused per-bin LDS counting sort + online-softmax aggregation ----------
// One 256-thread block per 64-node bin (R4-proven: VGPR 56, no spills).
// 4 waves x 16 nodes each, 4-deep gather pipeline (R6's 8-deep regressed: VGPR 76, occ -7).
__global__ __launch_bounds__(256) void bin_aggregate(
    const int* __restrict__ gcur, const int2* __restrict__ binned,
    const float* __restrict__ sbuf, const float* __restrict__ tbuf,
    const unsigned short* __restrict__ xmsg, float* __restrict__ out)
{
  __shared__ int nh[NPB];
  __shared__ int start_l[NPB];
  __shared__ int deg_l[NPB];
  __shared__ __align__(16) int2 sorted[CAPB];          // 24 KB
  __shared__ int s_lds[4][64];
  __shared__ __align__(16) float p_lds[4][64][4];

  const int tid = threadIdx.x;
  const int b = blockIdx.x;
  const int bbase = b * CAPB;
  const int cnt = min(gcur[b] - bbase, CAPB);

  if (tid < NPB) nh[tid] = 0;
  __syncthreads();

  // pass 1: per-node histogram (coalesced 8B reads; second pass hits L2)
  for (int i = tid; i < cnt; i += 256)
    atomicAdd(&nh[(binned[bbase + i].x >> 16) & 63], 1);
  __syncthreads();

  if (tid < 64) {                       // wave 0: exclusive prefix over 64 counters
    int v = nh[tid];
    int sc = v;
    #pragma unroll
    for (int off = 1; off < 64; off <<= 1) {
      int u = __shfl_up(sc, off);
      if (tid >= off) sc += u;
    }
    start_l[tid] = sc - v;
    deg_l[tid] = v;
    nh[tid] = 0;                        // reuse as rank counter
  }
  __syncthreads();

  // pass 2: counting sort into LDS (second global read hits L2)
  for (int i = tid; i < cnt; i += 256) {
    int2 e = binned[bbase + i];
    int tl = (e.x >> 16) & 63;
    int r = atomicAdd(&nh[tl], 1);
    sorted[start_l[tl] + r] = e;
  }
  __syncthreads();

  // ---- aggregation: 4 waves x 16 nodes each, edges from LDS ----
  const int lane = tid & 63;
  const int wave = tid >> 6;
  const int seg  = lane & 31;
  const int half = lane >> 5;
  const int hh4  = seg >> 3;            // head of this lane's 8 channels

  for (int ni = wave * 16; ni < wave * 16 + 16; ++ni) {
    const int n = b * NPB + ni;
    if (n >= N_NODES) break;            // wave-uniform; only last bin is short

    const int d   = deg_l[ni];
    const int rs0 = start_l[ni];

    float4 tn4 = *(const float4*)(tbuf + (size_t)n * 4);
    float tn[4] = {tn4.x, tn4.y, tn4.z, tn4.w};

    float m[4]    = {-INFINITY, -INFINITY, -INFINITY, -INFINITY};
    float psum[4] = {0.f, 0.f, 0.f, 0.f};
    float acc[8]  = {0.f, 0.f, 0.f, 0.f, 0.f, 0.f, 0.f, 0.f};

    for (int base2 = 0; base2 < d; base2 += 64) {
      const int cnt2 = min(64, d - base2);
      const bool act = lane < cnt2;

      float sc4[4] = {-INFINITY, -INFINITY, -INFINITY, -INFINITY};
      int s = 0;
      if (act) {
        int2 ev = sorted[rs0 + base2 + lane];
        s = ev.x & 0xffff;
        float v = __int_as_float(ev.y);
        float4 sv4 = *(const float4*)(sbuf + (size_t)s * 4);
        float svv[4] = {sv4.x, sv4.y, sv4.z, sv4.w};
        #pragma unroll
        for (int hh = 0; hh < 4; ++hh) {
          float t = svv[hh] + tn[hh];
          t = (t > 0.f) ? t : 0.01f * t;           // leaky_relu
          sc4[hh] = t * v;
        }
      }

      float bm[4] = {sc4[0], sc4[1], sc4[2], sc4[3]};
      #pragma unroll
      for (int hh = 0; hh < 4; ++hh)
        #pragma unroll
        for (int off = 32; off; off >>= 1)
          bm[hh] = fmaxf(bm[hh], __shfl_xor(bm[hh], off));

      float p[4];
      #pragma unroll
      for (int hh = 0; hh < 4; ++hh) {
        float nm = fmaxf(m[hh], bm[hh]);
        float r = (m[hh] == -INFINITY) ? 0.f : __expf(m[hh] - nm);
        psum[hh] *= r;
        if (hh == hh4) {
          #pragma unroll
          for (int j = 0; j < 8; ++j) acc[j] *= r;
        }
        m[hh] = nm;
        p[hh] = act ? __expf(sc4[hh] - nm) : 0.f;
        psum[hh] += p[hh];
      }

      if (act) {
        s_lds[wave][lane] = s;
        *(float4*)(&p_lds[wave][lane][0]) = make_float4(p[0], p[1], p[2], p[3]);
      }
      __builtin_amdgcn_wave_barrier();

      int k = 0;
      for (; k + 8 <= cnt2; k += 8) {
        int sA = s_lds[wave][k + 0 + half];
        int sB = s_lds[wave][k + 2 + half];
        int sC = s_lds[wave][k + 4 + half];
        int sD = s_lds[wave][k + 6 + half];
        uint4 rA = *(const uint4*)(xmsg + (size_t)sA * CH + seg * 8);
        uint4 rB = *(const uint4*)(xmsg + (size_t)sB * CH + seg * 8);
        uint4 rC = *(const uint4*)(xmsg + (size_t)sC * CH + seg * 8);
        uint4 rD = *(const uint4*)(xmsg + (size_t)sD * CH + seg * 8);
        float qA = p_lds[wave][k + 0 + half][hh4];
        float qB = p_lds[wave][k + 2 + half][hh4];
        float qC = p_lds[wave][k + 4 + half][hh4];
        float qD = p_lds[wave][k + 6 + half][hh4];
        acc[0] = fmaf(qA, bf16_lo(rA.x), acc[0]); acc[1] = fmaf(qA, bf16_hi(rA.x), acc[1]);
        acc[2] = fmaf(qA, bf16_lo(rA.y), acc[2]); acc[3] = fmaf(qA, bf16_hi(rA.y), acc[3]);
        acc[4] = fmaf(qA, bf16_lo(rA.z), acc[4]); acc[5] = fmaf(qA, bf16_hi(rA.z), acc[5]);
        acc[6] = fmaf(qA, bf16_lo(rA.w), acc[6]); acc[7] = fmaf(qA, bf16_hi(rA.w), acc[7]);
        acc[0] = fmaf(qB, bf16_lo(rB.x), acc[0]); acc[1] = fmaf(qB, bf16_hi(rB.x), acc[1]);
        acc[2] = fmaf(qB, bf16_lo(rB.y), acc[2]); acc[3] = fmaf(qB, bf16_hi(rB.y), acc[3]);
        acc[4] = fmaf(qB, bf16_lo(rB.z), acc[4]); acc[5] = fmaf(qB, bf16_hi(rB.z), acc[5]);
        acc[6] = fmaf(qB, bf16_lo(rB.w), acc[6]); acc[7] = fmaf(qB, bf16_hi(rB.w), acc[7]);
        acc[0] = fmaf(qC, bf16_lo(rC.x), acc[0]); acc[1] = fmaf(qC, bf16_hi(rC.x), acc[1]);
        acc[2] = fmaf(qC, bf16_lo(rC.y), acc[2]); acc[3] = fmaf(qC, bf16_hi(rC.y), acc[3]);
        acc[4] = fmaf(qC, bf16_lo(rC.z), acc[4]); acc[5] = fmaf(qC, bf16_hi(rC.z), acc[5]);
        acc[6] = fmaf(qC, bf16_lo(rC.w), acc[6]); acc[7] = fmaf(qC, bf16_hi(rC.w), acc[7]);
        acc[0] = fmaf(qD, bf16_lo(rD.x), acc[0]); acc[1] = fmaf(qD, bf16_hi(rD.x), acc[1]);
        acc[2] = fmaf(qD, bf16_lo(rD.y), acc[2]); acc[3] = fmaf(qD, bf16_hi(rD.y), acc[3]);
        acc[4] = fmaf(qD, bf16_lo(rD.z), acc[4]); acc[5] = fmaf(qD, bf16_hi(rD.z), acc[5]);
        acc[6] = fmaf(qD, bf16_lo(rD.w), acc[6]); acc[7] = fmaf(qD, bf16_hi(rD.w), acc[7]);
      }
      for (; k < cnt2; k += 2) {
        int e = k + half;
        if (e < cnt2) {
          int sA = s_lds[wave][e];
          uint4 rA = *(const uint4*)(xmsg + (size_t)sA * CH + seg * 8);
          float qA = p_lds[wave][e][hh4];
          acc[0] = fmaf(qA, bf16_lo(rA.x), acc[0]); acc[1] = fmaf(qA, bf16_hi(rA.x), acc[1]);
          acc[2] = fmaf(qA, bf16_lo(rA.y), acc[2]); acc[3] = fmaf(qA, bf16_hi(rA.y), acc[3]);
          acc[4] = fmaf(qA, bf16_lo(rA.z), acc[4]); acc[5] = fmaf(qA, bf16_hi(rA.z), acc[5]);
          acc[6] = fmaf(qA, bf16_lo(rA.w), acc[6]); acc[7] = fmaf(qA, bf16_hi(rA.w), acc[7]);
        }
      }
      __builtin_amdgcn_wave_barrier();
    }

    #pragma unroll
    for (int j = 0; j < 8; ++j) acc[j] += __shfl_xor(acc[j], 32);
    #pragma unroll
    for (int hh = 0; hh < 4; ++hh)
      #pragma unroll
      for (int off = 32; off; off >>= 1)
        psum[hh] += __shfl_xor(psum[hh], off);

    float rsum = psum[hh4];
    float inv = (rsum > 0.f) ? 1.0f / rsum : 0.f;
    const int o = half * 4;
    float4 o4 = make_float4(acc[o+0]*inv, acc[o+1]*inv, acc[o+2]*inv, acc[o+3]*inv);
    *(float4*)(out + (size_t)n * CH + seg * 8 + half * 4) = o4;
  }
}

// ---------- launch ----------
extern "C" void kernel_launch(void* const* d_in, const int* in_sizes, int n_in,
                              void* d_out, int out_size, void* d_ws, size_t ws_size,
                              hipStream_t stream) {
  const float* x    = (const float*)d_in[0];
  const int*   etgt = (const int*)  d_in[1];
  const int*   esrc = (const int*)  d_in[2];
  const float* evl  = (const float*)d_in[3];
  const float* w    = (const float*)d_in[4];
  const float* aw   = (const float*)d_in[5];
  float* out = (float*)d_out;

  char* ws = (char*)d_ws;
  unsigned short* wb   = (unsigned short*)(ws);              //      65,536 B
  unsigned short* xmsg = (unsigned short*)(ws + 65536);      //  25,600,000 B
  float* sbuf     = (float*)(ws + 25665536);                 //     800,000 B
  float* tbuf     = (float*)(ws + 26465536);                 //     800,000 B
  int*   gcur     = (int*)  (ws + 27265536);                 //       4,096 B
  int2*  binned   = (int2*) (ws + 27269632);                 //  19,218,432 B
  // total used: 46,488,064 B

  convert_w_init<<<128, 256, 0, stream>>>(w, wb, gcur);
  gemm_scatter<<<NSCAT + GEMMB, 256, 0, stream>>>(x, wb, aw, xmsg, sbuf, tbuf,
                                                  etgt, esrc, evl, gcur, binned);
  bin_aggregate<<<BINS, 256, 0, stream>>>(gcur, binned, sbuf, tbuf, xmsg, out);
}